// Round 1
// baseline (346.651 us; speedup 1.0000x reference)
//
#include <hip/hip_runtime.h>

// Problem constants (from reference setup_inputs)
constexpr int NB  = 2;     // batch
constexpr int CC  = 64;    // in channels
constexpr int DD  = 16;
constexpr int HH  = 32;
constexpr int WW  = 32;
constexpr int KN_ = 27;    // 3x3x3 taps
constexpr int OC  = 64;    // out channels
constexpr int DHW = DD * HH * WW;       // 16384
constexpr int TILE_P = 64;              // positions per block
constexpr int PADP   = 68;              // LDS row stride for S (floats)

// ---------------------------------------------------------------------------
// Transpose input NCDHW -> NDHWC (channels contiguous per voxel)
__global__ __launch_bounds__(256) void k_transpose_in(const float* __restrict__ in,
                                                      float* __restrict__ out) {
    __shared__ float tile[64][65];
    int bid = blockIdx.x;
    int n   = bid >> 8;              // 256 voxel-tiles per batch
    int v0  = (bid & 255) << 6;      // 64 voxels per tile
    int t    = threadIdx.x;
    int lane = t & 63;
    int row  = t >> 6;               // 0..3
#pragma unroll
    for (int i = 0; i < 16; ++i) {
        int c = (i << 2) + row;
        tile[c][lane] = in[(n * CC + c) * DHW + v0 + lane];
    }
    __syncthreads();
#pragma unroll
    for (int i = 0; i < 16; ++i) {
        int v = (i << 2) + row;
        out[(size_t)(n * DHW + v0 + v) * CC + lane] = tile[lane][v];
    }
}

// Transpose weight (o,c,k) -> (k,c,o)
__global__ __launch_bounds__(256) void k_transpose_w(const float* __restrict__ w,
                                                     float* __restrict__ wt) {
    int f = blockIdx.x * 256 + threadIdx.x;   // f = (k*64 + c)*64 + o ; total 110592 = 432*256
    int o = f & 63;
    int c = (f >> 6) & 63;
    int k = f >> 12;
    wt[f] = w[(o * CC + c) * KN_ + k];
}

// ---------------------------------------------------------------------------
// Fused deformable-conv3d kernel.
// TR=true : inp is NDHWC (transposed), wt is [k][c][o]
// TR=false: inp is NCDHW (original),   wt is original weight (o,c,k)
template <bool TR>
__global__ __launch_bounds__(256) void k_main(const float* __restrict__ inp,
                                              const float* __restrict__ wt,
                                              const float* __restrict__ offs,
                                              float* __restrict__ out) {
    __shared__ float Slds[64][PADP];   // [c][p(swizzled)]
    __shared__ float Wlds[64 * 64];    // [c][o]

    int bid = blockIdx.x;
    int n   = bid >> 8;                // 256 position-tiles per batch
    int p0  = (bid & 255) * TILE_P;

    int t     = threadIdx.x;
    int cq    = t & 15;                // channel-quad id (sampling phase)
    int c0    = cq << 2;
    int pslot = t >> 4;                // 0..15
    int ob    = (t & 15) << 2;         // o-block base (gemm phase)
    int pb    = (t >> 4) << 2;         // p-block base (gemm phase)

    // per-thread swizzle for S writes (constant: depends only on cq)
    int swz_w = (((cq & 7) ^ (cq >> 3)) << 2);

    float acc[4][4] = {};

    const float* offbase = offs + (size_t)n * (KN_ * 3) * DHW;

    for (int k = 0; k < KN_; ++k) {
        // ---- stage W_k into LDS: Wlds[c*64+o] ----
        if (TR) {
            const float4* src = (const float4*)(wt + k * 4096);
#pragma unroll
            for (int i = 0; i < 4; ++i)
                ((float4*)Wlds)[t + i * 256] = src[t + i * 256];
        } else {
#pragma unroll
            for (int i = 0; i < 16; ++i) {
                int f = i * 256 + t;        // f = c*64 + o
                int o = f & 63;
                int c = f >> 6;
                Wlds[f] = wt[(o * CC + c) * KN_ + k];
            }
        }

        // ---- sampling: S[c][p] for this k ----
#pragma unroll
        for (int j = 0; j < 4; ++j) {
            int pl = pslot + 16 * j;       // 0..63
            int pa = p0 + pl;              // absolute position
            int d  = pa >> 10;
            int h  = (pa >> 5) & 31;
            int w  = pa & 31;

            float offz = offbase[(k * 3 + 0) * DHW + pa];
            float offy = offbase[(k * 3 + 1) * DHW + pa];
            float offx = offbase[(k * 3 + 2) * DHW + pa];

            // normalized grid coords (align_corners=False unnormalize)
            float gx = ((float)w - 15.5f + offx) * (1.0f / 15.5f);
            float gy = ((float)h - 15.5f + offy) * (1.0f / 15.5f);
            float gz = ((float)d - 7.5f  + offz) * (1.0f / 7.5f);
            float ix = ((gx + 1.0f) * (float)WW - 1.0f) * 0.5f;
            float iy = ((gy + 1.0f) * (float)HH - 1.0f) * 0.5f;
            float iz = ((gz + 1.0f) * (float)DD - 1.0f) * 0.5f;

            float xf = floorf(ix), yf = floorf(iy), zf = floorf(iz);
            float fx = ix - xf, fy = iy - yf, fz = iz - zf;
            int x0 = (int)xf, y0 = (int)yf, z0 = (int)zf;

            float wx0 = 1.0f - fx, wx1 = fx;
            float wy0 = 1.0f - fy, wy1 = fy;
            float wz0 = 1.0f - fz, wz1 = fz;

            float s0 = 0.f, s1 = 0.f, s2 = 0.f, s3 = 0.f;
#pragma unroll
            for (int dz = 0; dz < 2; ++dz) {
                int zc = z0 + dz;
                if ((unsigned)zc >= (unsigned)DD) continue;
                float wz = dz ? wz1 : wz0;
#pragma unroll
                for (int dy = 0; dy < 2; ++dy) {
                    int yc = y0 + dy;
                    if ((unsigned)yc >= (unsigned)HH) continue;
                    float wzy = wz * (dy ? wy1 : wy0);
#pragma unroll
                    for (int dx = 0; dx < 2; ++dx) {
                        int xc = x0 + dx;
                        if ((unsigned)xc >= (unsigned)WW) continue;
                        float wf = wzy * (dx ? wx1 : wx0);
                        int vox = (zc * HH + yc) * WW + xc;
                        if (TR) {
                            const float4 v = *(const float4*)(inp + ((size_t)(n * DHW + vox) << 6) + c0);
                            s0 += wf * v.x; s1 += wf * v.y; s2 += wf * v.z; s3 += wf * v.w;
                        } else {
                            const float* b = inp + (size_t)(n * CC + c0) * DHW + vox;
                            s0 += wf * b[0];
                            s1 += wf * b[DHW];
                            s2 += wf * b[2 * DHW];
                            s3 += wf * b[3 * DHW];
                        }
                    }
                }
            }
            int plw = pl ^ swz_w;
            Slds[c0 + 0][plw] = s0;
            Slds[c0 + 1][plw] = s1;
            Slds[c0 + 2][plw] = s2;
            Slds[c0 + 3][plw] = s3;
        }

        __syncthreads();

        // ---- GEMM: acc[o 4][p 4] += W_k[o,c] * S_k[c,p] ----
#pragma unroll
        for (int c = 0; c < 64; ++c) {
            const int g = ((c >> 2) & 7) ^ (c >> 5);
            float4 wv = *(const float4*)(Wlds + c * 64 + ob);
            float4 sv = *(const float4*)(&Slds[c][pb ^ (g << 2)]);
            float wa[4] = {wv.x, wv.y, wv.z, wv.w};
            float sa[4] = {sv.x, sv.y, sv.z, sv.w};
#pragma unroll
            for (int i = 0; i < 4; ++i)
#pragma unroll
                for (int jj = 0; jj < 4; ++jj)
                    acc[i][jj] += wa[i] * sa[jj];
        }

        __syncthreads();
    }

    // ---- epilogue: out[n, o, p] ----
#pragma unroll
    for (int i = 0; i < 4; ++i) {
        float4 vv;
        vv.x = acc[i][0]; vv.y = acc[i][1]; vv.z = acc[i][2]; vv.w = acc[i][3];
        *(float4*)(out + (size_t)(n * OC + ob + i) * DHW + p0 + pb) = vv;
    }
}

// ---------------------------------------------------------------------------
extern "C" void kernel_launch(void* const* d_in, const int* in_sizes, int n_in,
                              void* d_out, int out_size, void* d_ws, size_t ws_size,
                              hipStream_t stream) {
    const float* inp = (const float*)d_in[0];   // (2,64,16,32,32)
    const float* off = (const float*)d_in[1];   // (2,81,16,32,32)
    const float* wgt = (const float*)d_in[2];   // (64,64,27)
    float* out = (float*)d_out;                 // (2,64,16,32,32)

    const size_t in_t_elems = (size_t)NB * DHW * CC;        // 2,097,152
    const size_t w_t_elems  = (size_t)KN_ * CC * OC;        // 110,592
    const size_t need = (in_t_elems + w_t_elems) * sizeof(float);

    if (ws_size >= need) {
        float* in_t = (float*)d_ws;
        float* w_t  = in_t + in_t_elems;
        k_transpose_in<<<dim3(NB * 256), dim3(256), 0, stream>>>(inp, in_t);
        k_transpose_w<<<dim3((KN_ * CC * OC) / 256), dim3(256), 0, stream>>>(wgt, w_t);
        k_main<true><<<dim3(NB * 256), dim3(256), 0, stream>>>(in_t, w_t, off, out);
    } else {
        // workspace too small: run directly on original layouts (slower, correct)
        k_main<false><<<dim3(NB * 256), dim3(256), 0, stream>>>(inp, wgt, off, out);
    }
}

// Round 2
// 128.716 us; speedup vs baseline: 2.6931x; 2.6931x over previous
//
#include <hip/hip_runtime.h>

typedef __attribute__((ext_vector_type(8))) short short8;
typedef __attribute__((ext_vector_type(4))) float floatx4;

constexpr int NB  = 2;
constexpr int CC  = 64;
constexpr int DD  = 16;
constexpr int HH  = 32;
constexpr int WW  = 32;
constexpr int KN_ = 27;
constexpr int OC  = 64;
constexpr int DHW = DD * HH * WW;   // 16384
constexpr int TILE_P = 32;

__device__ __forceinline__ unsigned short f2bf(float f) {
    unsigned int u = __float_as_uint(f);
    return (unsigned short)((u + 0x7fffu + ((u >> 16) & 1u)) >> 16);
}

// ---------------------------------------------------------------------------
// NCDHW f32 -> NDHWC bf16 (pairs packed in uint: low=even channel)
__global__ __launch_bounds__(256) void k_tin(const float* __restrict__ in,
                                             unsigned int* __restrict__ outu) {
    __shared__ float tile[64][65];
    int bid = blockIdx.x;
    int n   = bid >> 8;
    int v0  = (bid & 255) << 6;
    int t = threadIdx.x, lane = t & 63, row = t >> 6;
#pragma unroll
    for (int i = 0; i < 16; ++i) {
        int c = (i << 2) + row;
        tile[c][lane] = in[(size_t)(n * CC + c) * DHW + v0 + lane];
    }
    __syncthreads();
#pragma unroll
    for (int i = 0; i < 8; ++i) {
        int flat = i * 256 + t;
        int v = flat >> 5, cd = flat & 31;
        unsigned int lo = f2bf(tile[2 * cd][v]);
        unsigned int hi = f2bf(tile[2 * cd + 1][v]);
        outu[(size_t)(n * DHW + v0 + v) * 32 + cd] = lo | (hi << 16);
    }
}

// ---------------------------------------------------------------------------
// weight (o,c,k) f32 -> bf16 MFMA A-fragment stream:
// wf[(((k*2+cc)*4+wv)*64 + l)*8 + i] = W[o = wv*16 + (l&15)][c = cc*32 + (l>>4)*8 + i][k]
__global__ __launch_bounds__(256) void k_wf(const float* __restrict__ w,
                                            unsigned short* __restrict__ wf) {
    int f = blockIdx.x * 256 + threadIdx.x;   // 110592 total
    int i  = f & 7;
    int l  = (f >> 3) & 63;
    int wv = (f >> 9) & 3;
    int cc = (f >> 11) & 1;
    int k  = f >> 12;
    int o = wv * 16 + (l & 15);
    int c = cc * 32 + ((l >> 4) << 3) + i;
    wf[f] = f2bf(w[(o * CC + c) * KN_ + k]);
}

// ---------------------------------------------------------------------------
// Fused deformable sampling + MFMA GEMM.
// inp: NDHWC bf16 (64 ch per voxel, 128B rows); wf: A-frag stream; out: (n,o,p) f32
__global__ __launch_bounds__(256) void k_main(const unsigned short* __restrict__ inp,
                                              const unsigned short* __restrict__ wf,
                                              const float* __restrict__ offs,
                                              float* __restrict__ out) {
    __shared__ unsigned short S[2 * 32 * 64];   // [buf][p][c] bf16, 16B-chunk XOR swizzle

    int t   = threadIdx.x;
    int bid = blockIdx.x;
    int n   = bid >> 9;
    int p0  = (bid & 511) << 5;

    // sampling role: one p per 8 lanes, 8-channel group per lane
    int sp = t >> 3;            // 0..31
    int cg = t & 7;             // channel-group (8 ch = 16 B)
    int pa = p0 + sp;
    int dpos = pa >> 10, hpos = (pa >> 5) & 31, wpos = pa & 31;

    // mfma role
    int wv = t >> 6, l = t & 63;
    int lrow = l & 15, lk = l >> 4;

    floatx4 acc0 = {0.f, 0.f, 0.f, 0.f};
    floatx4 acc1 = {0.f, 0.f, 0.f, 0.f};

    const float* offb = offs + (size_t)n * (3 * KN_) * DHW + pa;
    const unsigned short* inb = inp + ((size_t)n * DHW << 6);

    // S write offset (ushort units): row sp, chunk (cg ^ (sp&7))
    const int woff = sp * 64 + ((cg ^ (sp & 7)) << 3);
    // S read offsets for B fragments: chunk j = cc*4 + lk, swizzled by row&7
    const int prow1 = 16 + lrow;
    const int roff00 = lrow  * 64 + (((0 + lk) ^ (lrow  & 7)) << 3);
    const int roff10 = lrow  * 64 + (((4 + lk) ^ (lrow  & 7)) << 3);
    const int roff01 = prow1 * 64 + (((0 + lk) ^ (prow1 & 7)) << 3);
    const int roff11 = prow1 * 64 + (((4 + lk) ^ (prow1 & 7)) << 3);

    for (int k = 0; k < KN_; ++k) {
        // ---- W fragments (independent of LDS; issue early) ----
        const short8 wa0 = *(const short8*)(wf + (((k << 3) + 0 + wv) << 9) + (l << 3));
        const short8 wa1 = *(const short8*)(wf + (((k << 3) + 4 + wv) << 9) + (l << 3));

        // ---- sampling: 8 channels for (k, pa) ----
        float oz = offb[(k * 3 + 0) * DHW];
        float oy = offb[(k * 3 + 1) * DHW];
        float ox = offb[(k * 3 + 2) * DHW];
        float ix = ((float)wpos + ox) * (32.0f / 31.0f) - 0.5f;
        float iy = ((float)hpos + oy) * (32.0f / 31.0f) - 0.5f;
        float iz = ((float)dpos + oz) * (16.0f / 15.0f) - 0.5f;
        float xf = floorf(ix), yf = floorf(iy), zf = floorf(iz);
        float fx = ix - xf, fy = iy - yf, fz = iz - zf;
        int x0 = (int)xf, y0 = (int)yf, z0 = (int)zf;

        float wx0 = ((unsigned)x0       < (unsigned)WW) ? 1.f - fx : 0.f;
        float wx1 = ((unsigned)(x0 + 1) < (unsigned)WW) ? fx       : 0.f;
        float wy0 = ((unsigned)y0       < (unsigned)HH) ? 1.f - fy : 0.f;
        float wy1 = ((unsigned)(y0 + 1) < (unsigned)HH) ? fy       : 0.f;
        float wz0 = ((unsigned)z0       < (unsigned)DD) ? 1.f - fz : 0.f;
        float wz1 = ((unsigned)(z0 + 1) < (unsigned)DD) ? fz       : 0.f;

        int xc0 = min(max(x0, 0), WW - 1), xc1 = min(max(x0 + 1, 0), WW - 1);
        int yc0 = min(max(y0, 0), HH - 1), yc1 = min(max(y0 + 1, 0), HH - 1);
        int zc0 = min(max(z0, 0), DD - 1), zc1 = min(max(z0 + 1, 0), DD - 1);

        float wzy00 = wz0 * wy0, wzy01 = wz0 * wy1, wzy10 = wz1 * wy0, wzy11 = wz1 * wy1;
        int b00 = (zc0 * HH + yc0) * WW, b01 = (zc0 * HH + yc1) * WW;
        int b10 = (zc1 * HH + yc0) * WW, b11 = (zc1 * HH + yc1) * WW;

        const int vox[8] = {b00 + xc0, b00 + xc1, b01 + xc0, b01 + xc1,
                            b10 + xc0, b10 + xc1, b11 + xc0, b11 + xc1};
        const float cwt[8] = {wzy00 * wx0, wzy00 * wx1, wzy01 * wx0, wzy01 * wx1,
                              wzy10 * wx0, wzy10 * wx1, wzy11 * wx0, wzy11 * wx1};

        float s0 = 0.f, s1 = 0.f, s2 = 0.f, s3 = 0.f, s4 = 0.f, s5 = 0.f, s6 = 0.f, s7 = 0.f;
#pragma unroll
        for (int cr = 0; cr < 8; ++cr) {
            const uint4 v = *(const uint4*)(inb + ((size_t)vox[cr] << 6) + (cg << 3));
            float wgt = cwt[cr];
            s0 += wgt * __uint_as_float(v.x << 16);
            s1 += wgt * __uint_as_float(v.x & 0xffff0000u);
            s2 += wgt * __uint_as_float(v.y << 16);
            s3 += wgt * __uint_as_float(v.y & 0xffff0000u);
            s4 += wgt * __uint_as_float(v.z << 16);
            s5 += wgt * __uint_as_float(v.z & 0xffff0000u);
            s6 += wgt * __uint_as_float(v.w << 16);
            s7 += wgt * __uint_as_float(v.w & 0xffff0000u);
        }

        uint4 pk;
        pk.x = (unsigned int)f2bf(s0) | ((unsigned int)f2bf(s1) << 16);
        pk.y = (unsigned int)f2bf(s2) | ((unsigned int)f2bf(s3) << 16);
        pk.z = (unsigned int)f2bf(s4) | ((unsigned int)f2bf(s5) << 16);
        pk.w = (unsigned int)f2bf(s6) | ((unsigned int)f2bf(s7) << 16);
        *(uint4*)(S + ((k & 1) << 11) + woff) = pk;

        __syncthreads();

        // ---- MFMA: acc[o16 x p16] over c=64 (two K=32 chunks) ----
        const unsigned short* Sb = S + ((k & 1) << 11);
        const short8 bf00 = *(const short8*)(Sb + roff00);
        const short8 bf10 = *(const short8*)(Sb + roff10);
        const short8 bf01 = *(const short8*)(Sb + roff01);
        const short8 bf11 = *(const short8*)(Sb + roff11);
        acc0 = __builtin_amdgcn_mfma_f32_16x16x32_bf16(wa0, bf00, acc0, 0, 0, 0);
        acc0 = __builtin_amdgcn_mfma_f32_16x16x32_bf16(wa1, bf10, acc0, 0, 0, 0);
        acc1 = __builtin_amdgcn_mfma_f32_16x16x32_bf16(wa0, bf01, acc1, 0, 0, 0);
        acc1 = __builtin_amdgcn_mfma_f32_16x16x32_bf16(wa1, bf11, acc1, 0, 0, 0);
        // double-buffered S: the lgkmcnt(0)+s_barrier at the top of the next
        // iteration orders these reads against the k+2 overwrite.
    }

    // ---- epilogue: out[n, o = wv*16 + lk*4 + r, p0 + lrow (+16)] ----
    float* ob = out + ((size_t)n * OC + (wv << 4) + (lk << 2)) * DHW + p0 + lrow;
#pragma unroll
    for (int r = 0; r < 4; ++r) {
        ob[r * DHW]      = acc0[r];
        ob[r * DHW + 16] = acc1[r];
    }
}

// ---------------------------------------------------------------------------
// Fallback (no workspace): original fp32 fused kernel, NCDHW layouts.
__global__ __launch_bounds__(256) void k_fallback(const float* __restrict__ inp,
                                                  const float* __restrict__ wt,
                                                  const float* __restrict__ offs,
                                                  float* __restrict__ out) {
    __shared__ float Slds[64][68];
    __shared__ float Wlds[64 * 64];
    int bid = blockIdx.x;
    int n = bid >> 8;
    int p0 = (bid & 255) * 64;
    int t = threadIdx.x;
    int cq = t & 15, c0 = cq << 2, pslot = t >> 4;
    int ob = (t & 15) << 2, pb = (t >> 4) << 2;
    int swz_w = (((cq & 7) ^ (cq >> 3)) << 2);
    float acc[4][4] = {};
    const float* offbase = offs + (size_t)n * (KN_ * 3) * DHW;
    for (int k = 0; k < KN_; ++k) {
#pragma unroll
        for (int i = 0; i < 16; ++i) {
            int f = i * 256 + t;
            int o = f & 63, c = f >> 6;
            Wlds[f] = wt[(o * CC + c) * KN_ + k];
        }
#pragma unroll
        for (int j = 0; j < 4; ++j) {
            int pl = pslot + 16 * j;
            int pa = p0 + pl;
            int d = pa >> 10, h = (pa >> 5) & 31, w = pa & 31;
            float offz = offbase[(k * 3 + 0) * DHW + pa];
            float offy = offbase[(k * 3 + 1) * DHW + pa];
            float offx = offbase[(k * 3 + 2) * DHW + pa];
            float ix = ((float)w + offx) * (32.0f / 31.0f) - 0.5f;
            float iy = ((float)h + offy) * (32.0f / 31.0f) - 0.5f;
            float iz = ((float)d + offz) * (16.0f / 15.0f) - 0.5f;
            float xf = floorf(ix), yf = floorf(iy), zf = floorf(iz);
            float fx = ix - xf, fy = iy - yf, fz = iz - zf;
            int x0 = (int)xf, y0 = (int)yf, z0 = (int)zf;
            float wx0 = 1.0f - fx, wx1 = fx, wy0 = 1.0f - fy, wy1 = fy, wz0 = 1.0f - fz, wz1 = fz;
            float s0 = 0.f, s1 = 0.f, s2 = 0.f, s3 = 0.f;
#pragma unroll
            for (int dz = 0; dz < 2; ++dz) {
                int zc = z0 + dz;
                if ((unsigned)zc >= (unsigned)DD) continue;
                float wz = dz ? wz1 : wz0;
#pragma unroll
                for (int dy = 0; dy < 2; ++dy) {
                    int yc = y0 + dy;
                    if ((unsigned)yc >= (unsigned)HH) continue;
                    float wzy = wz * (dy ? wy1 : wy0);
#pragma unroll
                    for (int dx = 0; dx < 2; ++dx) {
                        int xc = x0 + dx;
                        if ((unsigned)xc >= (unsigned)WW) continue;
                        float wf = wzy * (dx ? wx1 : wx0);
                        int vox = (zc * HH + yc) * WW + xc;
                        const float* b = inp + (size_t)(n * CC + c0) * DHW + vox;
                        s0 += wf * b[0]; s1 += wf * b[DHW];
                        s2 += wf * b[2 * DHW]; s3 += wf * b[3 * DHW];
                    }
                }
            }
            int plw = pl ^ swz_w;
            Slds[c0 + 0][plw] = s0; Slds[c0 + 1][plw] = s1;
            Slds[c0 + 2][plw] = s2; Slds[c0 + 3][plw] = s3;
        }
        __syncthreads();
#pragma unroll
        for (int c = 0; c < 64; ++c) {
            const int g = ((c >> 2) & 7) ^ (c >> 5);
            float4 wv = *(const float4*)(Wlds + c * 64 + ob);
            float4 sv = *(const float4*)(&Slds[c][pb ^ (g << 2)]);
            float wa[4] = {wv.x, wv.y, wv.z, wv.w};
            float sa[4] = {sv.x, sv.y, sv.z, sv.w};
#pragma unroll
            for (int i = 0; i < 4; ++i)
#pragma unroll
                for (int jj = 0; jj < 4; ++jj) acc[i][jj] += wa[i] * sa[jj];
        }
        __syncthreads();
    }
#pragma unroll
    for (int i = 0; i < 4; ++i) {
        float4 vv;
        vv.x = acc[i][0]; vv.y = acc[i][1]; vv.z = acc[i][2]; vv.w = acc[i][3];
        *(float4*)(out + (size_t)(n * OC + ob + i) * DHW + p0 + pb) = vv;
    }
}

// ---------------------------------------------------------------------------
extern "C" void kernel_launch(void* const* d_in, const int* in_sizes, int n_in,
                              void* d_out, int out_size, void* d_ws, size_t ws_size,
                              hipStream_t stream) {
    const float* inp = (const float*)d_in[0];
    const float* off = (const float*)d_in[1];
    const float* wgt = (const float*)d_in[2];
    float* out = (float*)d_out;

    const size_t in_bf_bytes = (size_t)NB * DHW * CC * 2;          // 4 MB
    const size_t wf_bytes    = (size_t)KN_ * 2 * 4 * 64 * 8 * 2;   // 216 KB
    if (ws_size >= in_bf_bytes + wf_bytes) {
        unsigned int*   in_t = (unsigned int*)d_ws;
        unsigned short* w_f  = (unsigned short*)((char*)d_ws + in_bf_bytes);
        k_tin<<<dim3(NB * 256), dim3(256), 0, stream>>>(inp, in_t);
        k_wf<<<dim3((KN_ * CC * OC) / 256), dim3(256), 0, stream>>>(wgt, w_f);
        k_main<<<dim3(NB * 512), dim3(256), 0, stream>>>((const unsigned short*)in_t, w_f, off, out);
    } else {
        k_fallback<<<dim3(NB * 256), dim3(256), 0, stream>>>(inp, wgt, off, out);
    }
}

// Round 3
// 119.904 us; speedup vs baseline: 2.8911x; 1.0735x over previous
//
#include <hip/hip_runtime.h>

typedef __attribute__((ext_vector_type(8))) short short8;
typedef __attribute__((ext_vector_type(8))) _Float16 half8;
typedef __attribute__((ext_vector_type(4))) float floatx4;

constexpr int NB  = 2;
constexpr int CC  = 64;
constexpr int DD  = 16;
constexpr int HH  = 32;
constexpr int WW  = 32;
constexpr int KN_ = 27;
constexpr int OC  = 64;
constexpr int DHW = DD * HH * WW;   // 16384

__device__ __forceinline__ unsigned short f2h(float f) {
    _Float16 h = (_Float16)f;
    return *(unsigned short*)&h;
}

// ---------------------------------------------------------------------------
// Prep kernel (merged):
//  blocks [0, 512)   : NCDHW f32 -> NDHWC f16  (64 ch contiguous per voxel)
//  blocks [512, 944) : weight (o,c,k) f32 -> f16 MFMA A-fragment stream
//    wf[(((k*2+cc)*4+wv)*64 + l)*8 + i] = W[o=wv*16+(l&15)][c=cc*32+(l>>4)*8+i][k]
__global__ __launch_bounds__(256) void k_prep(const float* __restrict__ in,
                                              const float* __restrict__ w,
                                              unsigned int* __restrict__ outu,
                                              unsigned short* __restrict__ wf) {
    int bid = blockIdx.x;
    int t = threadIdx.x;
    if (bid < 512) {
        __shared__ float tile[64][65];
        int n  = bid >> 8;
        int v0 = (bid & 255) << 6;
        int lane = t & 63, row = t >> 6;
#pragma unroll
        for (int i = 0; i < 16; ++i) {
            int c = (i << 2) + row;
            tile[c][lane] = in[(size_t)(n * CC + c) * DHW + v0 + lane];
        }
        __syncthreads();
#pragma unroll
        for (int i = 0; i < 8; ++i) {
            int flat = i * 256 + t;
            int v = flat >> 5, cd = flat & 31;
            unsigned int lo = f2h(tile[2 * cd][v]);
            unsigned int hi = f2h(tile[2 * cd + 1][v]);
            outu[(size_t)(n * DHW + v0 + v) * 32 + cd] = lo | (hi << 16);
        }
    } else {
        int f = (bid - 512) * 256 + t;   // 110592 total
        int i  = f & 7;
        int l  = (f >> 3) & 63;
        int wv = (f >> 9) & 3;
        int cc = (f >> 11) & 1;
        int k  = f >> 12;
        int o = wv * 16 + (l & 15);
        int c = cc * 32 + ((l >> 4) << 3) + i;
        wf[f] = f2h(w[(o * CC + c) * KN_ + k]);
    }
}

// ---------------------------------------------------------------------------
// Fused deformable sampling (f16 packed math) + f16 MFMA GEMM.
__global__ __launch_bounds__(256, 4) void k_main(const unsigned short* __restrict__ inp,
                                                 const unsigned short* __restrict__ wf,
                                                 const float* __restrict__ offs,
                                                 float* __restrict__ out) {
    __shared__ unsigned short S[2 * 32 * 64];   // [buf][p][c] f16, 16B-chunk XOR swizzle

    int t   = threadIdx.x;
    int bid = blockIdx.x;
    int n   = bid >> 9;
    int p0  = (bid & 511) << 5;

    // sampling role: one p per 8 lanes, 8-channel group per lane
    int sp = t >> 3;            // 0..31
    int cg = t & 7;             // channel-group (8 ch = 16 B)
    int pa = p0 + sp;
    int dpos = pa >> 10, hpos = (pa >> 5) & 31, wpos = pa & 31;

    // mfma role
    int wv = t >> 6, l = t & 63;
    int lrow = l & 15, lk = l >> 4;

    floatx4 acc0 = {0.f, 0.f, 0.f, 0.f};
    floatx4 acc1 = {0.f, 0.f, 0.f, 0.f};

    const float* offb = offs + (size_t)n * (3 * KN_) * DHW + pa;
    const unsigned short* inb = inp + ((size_t)n * DHW << 6);

    const int woff = sp * 64 + ((cg ^ (sp & 7)) << 3);
    const int prow1 = 16 + lrow;
    const int roff00 = lrow  * 64 + (((0 + lk) ^ (lrow  & 7)) << 3);
    const int roff10 = lrow  * 64 + (((4 + lk) ^ (lrow  & 7)) << 3);
    const int roff01 = prow1 * 64 + (((0 + lk) ^ (prow1 & 7)) << 3);
    const int roff11 = prow1 * 64 + (((4 + lk) ^ (prow1 & 7)) << 3);

    for (int k = 0; k < KN_; ++k) {
        // ---- W fragments (global, independent of LDS; issue early) ----
        const half8 wa0 = *(const half8*)(wf + (((k << 3) + 0 + wv) << 9) + (l << 3));
        const half8 wa1 = *(const half8*)(wf + (((k << 3) + 4 + wv) << 9) + (l << 3));

        // ---- sampling: 8 channels for (k, pa) ----
        float oz = offb[(k * 3 + 0) * DHW];
        float oy = offb[(k * 3 + 1) * DHW];
        float ox = offb[(k * 3 + 2) * DHW];
        float ix = ((float)wpos + ox) * (32.0f / 31.0f) - 0.5f;
        float iy = ((float)hpos + oy) * (32.0f / 31.0f) - 0.5f;
        float iz = ((float)dpos + oz) * (16.0f / 15.0f) - 0.5f;
        float xf = floorf(ix), yf = floorf(iy), zf = floorf(iz);
        float fx = ix - xf, fy = iy - yf, fz = iz - zf;
        int x0 = (int)xf, y0 = (int)yf, z0 = (int)zf;

        float wx0 = ((unsigned)x0       < (unsigned)WW) ? 1.f - fx : 0.f;
        float wx1 = ((unsigned)(x0 + 1) < (unsigned)WW) ? fx       : 0.f;
        float wy0 = ((unsigned)y0       < (unsigned)HH) ? 1.f - fy : 0.f;
        float wy1 = ((unsigned)(y0 + 1) < (unsigned)HH) ? fy       : 0.f;
        float wz0 = ((unsigned)z0       < (unsigned)DD) ? 1.f - fz : 0.f;
        float wz1 = ((unsigned)(z0 + 1) < (unsigned)DD) ? fz       : 0.f;

        int xc0 = min(max(x0, 0), WW - 1), xc1 = min(max(x0 + 1, 0), WW - 1);
        int yc0 = min(max(y0, 0), HH - 1), yc1 = min(max(y0 + 1, 0), HH - 1);
        int zc0 = min(max(z0, 0), DD - 1), zc1 = min(max(z0 + 1, 0), DD - 1);

        float wzy00 = wz0 * wy0, wzy01 = wz0 * wy1, wzy10 = wz1 * wy0, wzy11 = wz1 * wy1;
        int b00 = (zc0 * HH + yc0) * WW, b01 = (zc0 * HH + yc1) * WW;
        int b10 = (zc1 * HH + yc0) * WW, b11 = (zc1 * HH + yc1) * WW;

        const int vox[8] = {b00 + xc0, b00 + xc1, b01 + xc0, b01 + xc1,
                            b10 + xc0, b10 + xc1, b11 + xc0, b11 + xc1};
        const float cwt[8] = {wzy00 * wx0, wzy00 * wx1, wzy01 * wx0, wzy01 * wx1,
                              wzy10 * wx0, wzy10 * wx1, wzy11 * wx0, wzy11 * wx1};

        half8 acc = {0, 0, 0, 0, 0, 0, 0, 0};
#pragma unroll
        for (int cr = 0; cr < 8; ++cr) {
            const half8 v = *(const half8*)(inb + ((size_t)vox[cr] << 6) + (cg << 3));
            _Float16 wh = (_Float16)cwt[cr];
            half8 w8 = {wh, wh, wh, wh, wh, wh, wh, wh};
            acc += v * w8;     // 4x v_pk_fma_f16
        }
        *(half8*)(S + ((k & 1) << 11) + woff) = acc;

        __syncthreads();

        // ---- MFMA: acc[o16 x p16] over c=64 (two K=32 chunks) ----
        const unsigned short* Sb = S + ((k & 1) << 11);
        const half8 bf00 = *(const half8*)(Sb + roff00);
        const half8 bf10 = *(const half8*)(Sb + roff10);
        const half8 bf01 = *(const half8*)(Sb + roff01);
        const half8 bf11 = *(const half8*)(Sb + roff11);
        acc0 = __builtin_amdgcn_mfma_f32_16x16x32_f16(wa0, bf00, acc0, 0, 0, 0);
        acc0 = __builtin_amdgcn_mfma_f32_16x16x32_f16(wa1, bf10, acc0, 0, 0, 0);
        acc1 = __builtin_amdgcn_mfma_f32_16x16x32_f16(wa0, bf01, acc1, 0, 0, 0);
        acc1 = __builtin_amdgcn_mfma_f32_16x16x32_f16(wa1, bf11, acc1, 0, 0, 0);
        // double-buffered S: next iteration's barrier orders reads vs k+2 overwrite
    }

    // ---- epilogue: out[n, o = wv*16 + lk*4 + r, p0 + lrow (+16)] ----
    float* ob = out + ((size_t)n * OC + (wv << 4) + (lk << 2)) * DHW + p0 + lrow;
#pragma unroll
    for (int r = 0; r < 4; ++r) {
        ob[r * DHW]      = acc0[r];
        ob[r * DHW + 16] = acc1[r];
    }
}

// ---------------------------------------------------------------------------
// Fallback (no workspace): fp32 fused kernel, original layouts.
__global__ __launch_bounds__(256) void k_fallback(const float* __restrict__ inp,
                                                  const float* __restrict__ wt,
                                                  const float* __restrict__ offs,
                                                  float* __restrict__ out) {
    __shared__ float Slds[64][68];
    __shared__ float Wlds[64 * 64];
    int bid = blockIdx.x;
    int n = bid >> 8;
    int p0 = (bid & 255) * 64;
    int t = threadIdx.x;
    int cq = t & 15, c0 = cq << 2, pslot = t >> 4;
    int ob = (t & 15) << 2, pb = (t >> 4) << 2;
    int swz_w = (((cq & 7) ^ (cq >> 3)) << 2);
    float acc[4][4] = {};
    const float* offbase = offs + (size_t)n * (KN_ * 3) * DHW;
    for (int k = 0; k < KN_; ++k) {
#pragma unroll
        for (int i = 0; i < 16; ++i) {
            int f = i * 256 + t;
            int o = f & 63, c = f >> 6;
            Wlds[f] = wt[(o * CC + c) * KN_ + k];
        }
#pragma unroll
        for (int j = 0; j < 4; ++j) {
            int pl = pslot + 16 * j;
            int pa = p0 + pl;
            int d = pa >> 10, h = (pa >> 5) & 31, w = pa & 31;
            float offz = offbase[(k * 3 + 0) * DHW + pa];
            float offy = offbase[(k * 3 + 1) * DHW + pa];
            float offx = offbase[(k * 3 + 2) * DHW + pa];
            float ix = ((float)w + offx) * (32.0f / 31.0f) - 0.5f;
            float iy = ((float)h + offy) * (32.0f / 31.0f) - 0.5f;
            float iz = ((float)d + offz) * (16.0f / 15.0f) - 0.5f;
            float xf = floorf(ix), yf = floorf(iy), zf = floorf(iz);
            float fx = ix - xf, fy = iy - yf, fz = iz - zf;
            int x0 = (int)xf, y0 = (int)yf, z0 = (int)zf;
            float wx0 = 1.0f - fx, wx1 = fx, wy0 = 1.0f - fy, wy1 = fy, wz0 = 1.0f - fz, wz1 = fz;
            float s0 = 0.f, s1 = 0.f, s2 = 0.f, s3 = 0.f;
#pragma unroll
            for (int dz = 0; dz < 2; ++dz) {
                int zc = z0 + dz;
                if ((unsigned)zc >= (unsigned)DD) continue;
                float wz = dz ? wz1 : wz0;
#pragma unroll
                for (int dy = 0; dy < 2; ++dy) {
                    int yc = y0 + dy;
                    if ((unsigned)yc >= (unsigned)HH) continue;
                    float wzy = wz * (dy ? wy1 : wy0);
#pragma unroll
                    for (int dx = 0; dx < 2; ++dx) {
                        int xc = x0 + dx;
                        if ((unsigned)xc >= (unsigned)WW) continue;
                        float wf = wzy * (dx ? wx1 : wx0);
                        int vox = (zc * HH + yc) * WW + xc;
                        const float* b = inp + (size_t)(n * CC + c0) * DHW + vox;
                        s0 += wf * b[0]; s1 += wf * b[DHW];
                        s2 += wf * b[2 * DHW]; s3 += wf * b[3 * DHW];
                    }
                }
            }
            int plw = pl ^ swz_w;
            Slds[c0 + 0][plw] = s0; Slds[c0 + 1][plw] = s1;
            Slds[c0 + 2][plw] = s2; Slds[c0 + 3][plw] = s3;
        }
        __syncthreads();
#pragma unroll
        for (int c = 0; c < 64; ++c) {
            const int g = ((c >> 2) & 7) ^ (c >> 5);
            float4 wv = *(const float4*)(Wlds + c * 64 + ob);
            float4 sv = *(const float4*)(&Slds[c][pb ^ (g << 2)]);
            float wa[4] = {wv.x, wv.y, wv.z, wv.w};
            float sa[4] = {sv.x, sv.y, sv.z, sv.w};
#pragma unroll
            for (int i = 0; i < 4; ++i)
#pragma unroll
                for (int jj = 0; jj < 4; ++jj) acc[i][jj] += wa[i] * sa[jj];
        }
        __syncthreads();
    }
#pragma unroll
    for (int i = 0; i < 4; ++i) {
        float4 vv;
        vv.x = acc[i][0]; vv.y = acc[i][1]; vv.z = acc[i][2]; vv.w = acc[i][3];
        *(float4*)(out + (size_t)(n * OC + ob + i) * DHW + p0 + pb) = vv;
    }
}

// ---------------------------------------------------------------------------
extern "C" void kernel_launch(void* const* d_in, const int* in_sizes, int n_in,
                              void* d_out, int out_size, void* d_ws, size_t ws_size,
                              hipStream_t stream) {
    const float* inp = (const float*)d_in[0];
    const float* off = (const float*)d_in[1];
    const float* wgt = (const float*)d_in[2];
    float* out = (float*)d_out;

    const size_t in_f16_bytes = (size_t)NB * DHW * CC * 2;           // 4 MB
    const size_t wf_bytes     = (size_t)KN_ * 2 * 4 * 64 * 8 * 2;    // 216 KB
    if (ws_size >= in_f16_bytes + wf_bytes) {
        unsigned int*   in_t = (unsigned int*)d_ws;
        unsigned short* w_f  = (unsigned short*)((char*)d_ws + in_f16_bytes);
        k_prep<<<dim3(512 + 432), dim3(256), 0, stream>>>(inp, wgt, in_t, w_f);
        k_main<<<dim3(NB * 512), dim3(256), 0, stream>>>((const unsigned short*)in_t, w_f, off, out);
    } else {
        k_fallback<<<dim3(NB * 256), dim3(256), 0, stream>>>(inp, wgt, off, out);
    }
}